// Round 1
// baseline (183.633 us; speedup 1.0000x reference)
//
#include <hip/hip_runtime.h>
#include <stdint.h>

#define B_ 32
#define S_ 8192
#define D_ 128
#define H_ 256

typedef __attribute__((ext_vector_type(4))) float f32x4;
typedef __attribute__((ext_vector_type(8))) short bf16x8;
typedef __attribute__((ext_vector_type(4))) unsigned int u32x4;
typedef __attribute__((ext_vector_type(4))) unsigned short u16x4;

__device__ __forceinline__ unsigned short f2bf(float f) {
    union { float f; unsigned int u; } v; v.f = f;
    unsigned int r = v.u + 0x7fffu + ((v.u >> 16) & 1u);
    return (unsigned short)(r >> 16);
}
__device__ __forceinline__ float bf2f(unsigned short u) {
    union { unsigned int u; float f; } v; v.u = ((unsigned int)u) << 16;
    return v.f;
}
__device__ __forceinline__ float silu_f(float v) {
    return v / (1.0f + __expf(-v));
}

// ---------------- prep: bf16-convert + transpose weights ----------------
// w1t[b][h][d] = W1[b][d][h]  (so GEMM2 B-frags are contiguous-k)
// w2t[b][d][h] = W2[b][h][d]  (so GEMM3 B-frags are contiguous-k)
__global__ void k_prep(const float* __restrict__ Wq, const float* __restrict__ W1,
                       const float* __restrict__ W2,
                       unsigned short* __restrict__ wq_bf,
                       unsigned short* __restrict__ w1t,
                       unsigned short* __restrict__ w2t) {
    int idx = blockIdx.x * 256 + threadIdx.x;   // grid = B*H*D / 256
    {
        int b = idx >> 15, rem = idx & 32767;
        int h = rem >> 7, d = rem & 127;
        w1t[idx] = f2bf(W1[((size_t)(b * D_ + d)) * H_ + h]);
    }
    {
        int b = idx >> 15, rem = idx & 32767;
        int d = rem >> 8, h = rem & 255;
        w2t[idx] = f2bf(W2[((size_t)(b * H_ + h)) * D_ + d]);
    }
    if (idx < D_ * D_) wq_bf[idx] = f2bf(Wq[idx]);
}

// ---------------- GEMM1: q_pre = silu(x @ Wq^T), + column sumsq partials ----
__global__ __launch_bounds__(256, 2) void k_qproj(
        const float* __restrict__ x, const unsigned short* __restrict__ wq_bf,
        unsigned short* __restrict__ q_ws, float* __restrict__ part) {
    __shared__ __align__(16) unsigned short lds_a[128 * 128];  // x tile bf16 (swizzled)
    __shared__ __align__(16) unsigned short lds_b[128 * 128];  // Wq [e][d] bf16 (swizzled)
    __shared__ float lds_ss[4][128];

    int tid = threadIdx.x;
    int lane = tid & 63, w = tid >> 6;
    int c15 = lane & 15;
    int blk = blockIdx.x;
    int b = blk >> 6, st = blk & 63;
    size_t rowbase = (size_t)b * S_ + (size_t)st * 128;
    const float* xg = x + rowbase * D_;

    char* pA = (char*)lds_a;
    char* pB = (char*)lds_b;

    // stage Wq (plain copy, swizzle on 16B chunks)
#pragma unroll
    for (int i = 0; i < 8; i++) {
        int idx = tid + i * 256;
        int row = idx >> 4, cb = idx & 15;
        u32x4 v = *reinterpret_cast<const u32x4*>(wq_bf + row * 128 + cb * 8);
        *reinterpret_cast<u32x4*>(pB + row * 256 + (((unsigned)cb ^ (unsigned)(row & 7)) << 4)) = v;
    }
    // stage x tile: fp32 -> bf16, swizzled 8B writes
#pragma unroll
    for (int i = 0; i < 16; i++) {
        int idx = tid + i * 256;           // 4096 float4 chunks
        int row = idx >> 5, c4 = idx & 31;
        f32x4 v = *reinterpret_cast<const f32x4*>(xg + (size_t)row * 128 + c4 * 4);
        u16x4 o;
        o[0] = f2bf(v[0]); o[1] = f2bf(v[1]); o[2] = f2bf(v[2]); o[3] = f2bf(v[3]);
        *reinterpret_cast<u16x4*>(pA + row * 256 + ((c4 * 8) ^ ((row & 7) << 4))) = o;
    }
    __syncthreads();

    f32x4 acc[2][8];
#pragma unroll
    for (int m = 0; m < 2; m++)
#pragma unroll
        for (int n = 0; n < 8; n++) acc[m][n] = (f32x4)0.0f;

#pragma unroll
    for (int kk = 0; kk < 4; kk++) {
        int kb = kk * 64 + ((lane >> 4) << 4);   // byte offset of this lane's k-slice
        bf16x8 a[2];
#pragma unroll
        for (int m = 0; m < 2; m++) {
            int row = (w << 5) + (m << 4) + c15;
            a[m] = *reinterpret_cast<const bf16x8*>(pA + row * 256 + (kb ^ ((row & 7) << 4)));
        }
#pragma unroll
        for (int n = 0; n < 8; n++) {
            int rowb = (n << 4) + c15;
            bf16x8 bb = *reinterpret_cast<const bf16x8*>(pB + rowb * 256 + (kb ^ ((rowb & 7) << 4)));
#pragma unroll
            for (int m = 0; m < 2; m++)
                acc[m][n] = __builtin_amdgcn_mfma_f32_16x16x32_bf16(a[m], bb, acc[m][n], 0, 0, 0);
        }
    }

    // epilogue: silu -> bf16 q store + column sumsq
    float ss[8];
#pragma unroll
    for (int n = 0; n < 8; n++) ss[n] = 0.0f;
    unsigned short* qg = q_ws + rowbase * D_;
#pragma unroll
    for (int m = 0; m < 2; m++) {
#pragma unroll
        for (int n = 0; n < 8; n++) {
            int col = (n << 4) + c15;
#pragma unroll
            for (int r = 0; r < 4; r++) {
                int row = (w << 5) + (m << 4) + ((lane >> 4) << 2) + r;
                float v = silu_f(acc[m][n][r]);
                unsigned short qb = f2bf(v);
                qg[(size_t)row * 128 + col] = qb;
                float vq = bf2f(qb);
                ss[n] += vq * vq;
            }
        }
    }
#pragma unroll
    for (int n = 0; n < 8; n++) {
        float v = ss[n];
        v += __shfl_xor(v, 16, 64);
        v += __shfl_xor(v, 32, 64);
        if (lane < 16) lds_ss[w][(n << 4) + lane] = v;
    }
    __syncthreads();
    if (tid < 128) {
        float s = lds_ss[0][tid] + lds_ss[1][tid] + lds_ss[2][tid] + lds_ss[3][tid];
        part[((size_t)b * 64 + st) * 128 + tid] = s;   // deterministic partials
    }
}

// ---------------- scale = 1/max(||q_col||, 1e-12) ----------------
__global__ void k_scale(const float* __restrict__ part, float* __restrict__ scale) {
    int idx = blockIdx.x * 256 + threadIdx.x;   // B*D = 4096
    int b = idx >> 7, e = idx & 127;
    const float* p = part + (size_t)b * 64 * 128 + e;
    float s = 0.0f;
    for (int t = 0; t < 64; t++) s += p[t * 128];
    scale[idx] = 1.0f / fmaxf(sqrtf(s), 1e-12f);
}

// ---------------- fused per-batch MLP + LN + residual ----------------
__global__ __launch_bounds__(256, 2) void k_mlp(
        const unsigned short* __restrict__ q_ws, const float* __restrict__ scale,
        const unsigned short* __restrict__ w1t, const unsigned short* __restrict__ w2t,
        const float* __restrict__ b1, const float* __restrict__ b2,
        const float* __restrict__ gamma, const float* __restrict__ beta,
        float* __restrict__ out) {
    __shared__ __align__(16) unsigned short lds_q[128 * 128];  // scaled q bf16, swizzled
    __shared__ __align__(16) unsigned short lds_w1[64 * 128];  // [h][d], rows h of chunk
    __shared__ __align__(16) unsigned short lds_w2[128 * 64];  // [d][hchunk]
    __shared__ __align__(16) unsigned short lds_h[128 * 64];   // [s][hchunk]

    int tid = threadIdx.x;
    int lane = tid & 63, w = tid >> 6;
    int c15 = lane & 15;
    int blk = blockIdx.x;
    int b = blk >> 6, st = blk & 63;
    size_t rowbase = (size_t)b * S_ + (size_t)st * 128;

    char* pQ = (char*)lds_q;
    char* pW1 = (char*)lds_w1;
    char* pW2 = (char*)lds_w2;
    char* pH = (char*)lds_h;

    // stage q: bf16 load, scale per column, bf16 repack, swizzled store
    const unsigned short* qg = q_ws + rowbase * D_;
    const float* sc = scale + b * 128;
#pragma unroll
    for (int i = 0; i < 8; i++) {
        int idx = tid + i * 256;
        int row = idx >> 4, cb = idx & 15;
        u32x4 v = *reinterpret_cast<const u32x4*>(qg + (size_t)row * 128 + cb * 8);
        const unsigned short* pv = (const unsigned short*)&v;
        union { unsigned short s[8]; u32x4 v; } ou;
#pragma unroll
        for (int t = 0; t < 8; t++) ou.s[t] = f2bf(bf2f(pv[t]) * sc[cb * 8 + t]);
        *reinterpret_cast<u32x4*>(pQ + row * 256 + (((unsigned)cb ^ (unsigned)(row & 7)) << 4)) = ou.v;
    }

    f32x4 acco[2][8];
#pragma unroll
    for (int m = 0; m < 2; m++)
#pragma unroll
        for (int n = 0; n < 8; n++) acco[m][n] = (f32x4)0.0f;

    for (int hc = 0; hc < 4; hc++) {
        // stage W1 chunk: rows h (64) x d (128)
#pragma unroll
        for (int i = 0; i < 4; i++) {
            int idx = tid + i * 256;
            int row = idx >> 4, cb = idx & 15;
            u32x4 v = *reinterpret_cast<const u32x4*>(
                w1t + (((size_t)b * H_ + hc * 64 + row) << 7) + cb * 8);
            *reinterpret_cast<u32x4*>(pW1 + row * 256 + (((unsigned)cb ^ (unsigned)(row & 7)) << 4)) = v;
        }
        // stage W2 chunk: rows d (128) x hchunk (64)
#pragma unroll
        for (int i = 0; i < 4; i++) {
            int idx = tid + i * 256;
            int row = idx >> 3, cb = idx & 7;
            u32x4 v = *reinterpret_cast<const u32x4*>(
                w2t + (((size_t)b * D_ + row) << 8) + hc * 64 + cb * 8);
            *reinterpret_cast<u32x4*>(pW2 + row * 128 + (((unsigned)cb ^ (unsigned)(row & 7)) << 4)) = v;
        }
        float b1g[4];
#pragma unroll
        for (int n = 0; n < 4; n++) b1g[n] = b1[b * H_ + hc * 64 + (n << 4) + c15];
        __syncthreads();

        // GEMM2: h_chunk = q @ W1c   (K = 128)
        f32x4 acch[2][4];
#pragma unroll
        for (int m = 0; m < 2; m++)
#pragma unroll
            for (int n = 0; n < 4; n++) acch[m][n] = (f32x4)0.0f;
#pragma unroll
        for (int kk = 0; kk < 4; kk++) {
            int kb = kk * 64 + ((lane >> 4) << 4);
            bf16x8 a[2];
#pragma unroll
            for (int m = 0; m < 2; m++) {
                int row = (w << 5) + (m << 4) + c15;
                a[m] = *reinterpret_cast<const bf16x8*>(pQ + row * 256 + (kb ^ ((row & 7) << 4)));
            }
#pragma unroll
            for (int n = 0; n < 4; n++) {
                int rowb = (n << 4) + c15;
                bf16x8 bb = *reinterpret_cast<const bf16x8*>(pW1 + rowb * 256 + (kb ^ ((rowb & 7) << 4)));
#pragma unroll
                for (int m = 0; m < 2; m++)
                    acch[m][n] = __builtin_amdgcn_mfma_f32_16x16x32_bf16(a[m], bb, acch[m][n], 0, 0, 0);
            }
        }
        // h = silu(h + b1) -> bf16 -> lds_h (scattered b16 writes, swizzled)
#pragma unroll
        for (int m = 0; m < 2; m++) {
#pragma unroll
            for (int n = 0; n < 4; n++) {
                int col = (n << 4) + c15;
#pragma unroll
                for (int r = 0; r < 4; r++) {
                    int row = (w << 5) + (m << 4) + ((lane >> 4) << 2) + r;
                    unsigned short hb = f2bf(silu_f(acch[m][n][r] + b1g[n]));
                    *reinterpret_cast<unsigned short*>(pH + row * 128 + ((col * 2) ^ ((row & 7) << 4))) = hb;
                }
            }
        }
        __syncthreads();

        // GEMM3: acco += h_chunk @ W2c   (K = 64)
#pragma unroll
        for (int kk = 0; kk < 2; kk++) {
            int kb = kk * 64 + ((lane >> 4) << 4);
            bf16x8 a[2];
#pragma unroll
            for (int m = 0; m < 2; m++) {
                int row = (w << 5) + (m << 4) + c15;
                a[m] = *reinterpret_cast<const bf16x8*>(pH + row * 128 + (kb ^ ((row & 7) << 4)));
            }
#pragma unroll
            for (int n = 0; n < 8; n++) {
                int rowb = (n << 4) + c15;
                bf16x8 bb = *reinterpret_cast<const bf16x8*>(pW2 + rowb * 128 + (kb ^ ((rowb & 7) << 4)));
#pragma unroll
                for (int m = 0; m < 2; m++)
                    acco[m][n] = __builtin_amdgcn_mfma_f32_16x16x32_bf16(a[m], bb, acco[m][n], 0, 0, 0);
            }
        }
        __syncthreads();
    }

    // epilogue: LayerNorm over D + residual q
    float g[8], be[8], b2v[8];
#pragma unroll
    for (int n = 0; n < 8; n++) {
        int col = (n << 4) + c15;
        g[n] = gamma[b * 128 + col];
        be[n] = beta[b * 128 + col];
        b2v[n] = b2[b * 128 + col];
    }
    float* og = out + rowbase * D_;
#pragma unroll
    for (int m = 0; m < 2; m++) {
#pragma unroll
        for (int r = 0; r < 4; r++) {
            int row = (w << 5) + (m << 4) + ((lane >> 4) << 2) + r;
            float v[8];
            float s = 0.0f, s2 = 0.0f;
#pragma unroll
            for (int n = 0; n < 8; n++) {
                v[n] = acco[m][n][r] + b2v[n];
                s += v[n]; s2 += v[n] * v[n];
            }
            s += __shfl_xor(s, 1, 64);  s2 += __shfl_xor(s2, 1, 64);
            s += __shfl_xor(s, 2, 64);  s2 += __shfl_xor(s2, 2, 64);
            s += __shfl_xor(s, 4, 64);  s2 += __shfl_xor(s2, 4, 64);
            s += __shfl_xor(s, 8, 64);  s2 += __shfl_xor(s2, 8, 64);
            float mu = s * (1.0f / 128.0f);
            float var = s2 * (1.0f / 128.0f) - mu * mu;
            float rstd = rsqrtf(var + 1e-5f);
#pragma unroll
            for (int n = 0; n < 8; n++) {
                int col = (n << 4) + c15;
                float qv = bf2f(*reinterpret_cast<const unsigned short*>(
                    pQ + row * 256 + ((col * 2) ^ ((row & 7) << 4))));
                og[(size_t)row * 128 + col] = (v[n] - mu) * rstd * g[n] + be[n] + qv;
            }
        }
    }
}

extern "C" void kernel_launch(void* const* d_in, const int* in_sizes, int n_in,
                              void* d_out, int out_size, void* d_ws, size_t ws_size,
                              hipStream_t stream) {
    (void)in_sizes; (void)n_in; (void)out_size; (void)ws_size;
    const float* x     = (const float*)d_in[0];
    const float* Wq    = (const float*)d_in[1];
    const float* W1    = (const float*)d_in[2];
    const float* b1    = (const float*)d_in[3];
    const float* W2    = (const float*)d_in[4];
    const float* b2    = (const float*)d_in[5];
    const float* gamma = (const float*)d_in[6];
    const float* beta  = (const float*)d_in[7];
    float* out = (float*)d_out;

    char* ws = (char*)d_ws;
    // ws layout (all 256B aligned); total ~70 MB
    unsigned short* wq_bf = (unsigned short*)(ws);
    unsigned short* w1t   = (unsigned short*)(ws + 32768);
    unsigned short* w2t   = (unsigned short*)(ws + 32768 + 2097152);
    float* part           = (float*)(ws + 32768 + 2 * 2097152);
    float* scale          = (float*)(ws + 32768 + 2 * 2097152 + 1048576);
    unsigned short* q_ws  = (unsigned short*)(ws + 32768 + 2 * 2097152 + 1048576 + 16384);

    hipLaunchKernelGGL(k_prep, dim3(4096), dim3(256), 0, stream, Wq, W1, W2, wq_bf, w1t, w2t);
    hipLaunchKernelGGL(k_qproj, dim3(2048), dim3(256), 0, stream, x, wq_bf, q_ws, part);
    hipLaunchKernelGGL(k_scale, dim3(16), dim3(256), 0, stream, part, scale);
    hipLaunchKernelGGL(k_mlp, dim3(2048), dim3(256), 0, stream,
                       q_ws, scale, w1t, w2t, b1, b2, gamma, beta, out);
}

// Round 2
// 147.397 us; speedup vs baseline: 1.2458x; 1.2458x over previous
//
#include <hip/hip_runtime.h>
#include <stdint.h>

#define B_ 32
#define S_ 8192
#define D_ 128
#define H_ 256

typedef __attribute__((ext_vector_type(4))) float f32x4;
typedef __attribute__((ext_vector_type(8))) short bf16x8;
typedef __attribute__((ext_vector_type(4))) unsigned int u32x4;

__device__ __forceinline__ unsigned short f2bf(float f) {
    union { float f; unsigned int u; } v; v.f = f;
    unsigned int r = v.u + 0x7fffu + ((v.u >> 16) & 1u);
    return (unsigned short)(r >> 16);
}
__device__ __forceinline__ float bf2f(unsigned short u) {
    union { unsigned int u; float f; } v; v.u = ((unsigned int)u) << 16;
    return v.f;
}
__device__ __forceinline__ float silu_f(float v) {
    return v / (1.0f + __expf(-v));
}
__device__ __forceinline__ unsigned int cvtpk(float lo, float hi) {
    unsigned int r;
    asm("v_cvt_pk_bf16_f32 %0, %1, %2" : "=v"(r) : "v"(lo), "v"(hi));
    return r;
}
__device__ __forceinline__ void gl16(const void* g, void* l) {
    __builtin_amdgcn_global_load_lds(
        (const __attribute__((address_space(1))) unsigned int*)g,
        (__attribute__((address_space(3))) unsigned int*)l, 16, 0, 0);
}

// ---------------- prep: bf16 transposes; W2 -> pre-swizzled images ----------------
// w1t[b][h][d] plain (k_wscale swizzles in-place); w2s[b][hc] 16KB images [d][h-chunk^swz]
__global__ void k_prep(const float* __restrict__ Wq, const float* __restrict__ W1,
                       const float* __restrict__ W2,
                       unsigned short* __restrict__ wq_bf,
                       unsigned short* __restrict__ w1t,
                       unsigned short* __restrict__ w2s) {
    __shared__ __align__(16) unsigned short tile[64 * 64];
    int t = threadIdx.x, blk = blockIdx.x;
    if (blk < 512) {                       // W2 [b][h][d] -> w2s image [d][h] swizzled
        int b = blk >> 4, ht = (blk >> 2) & 3, dt = blk & 3;
        int h0 = ht * 64, d0 = dt * 32;
#pragma unroll
        for (int i = 0; i < 2; i++) {
            int idx = t + i * 256;                 // 0..511
            int h = idx >> 3, d4 = (idx & 7) * 4;
            f32x4 v = *(const f32x4*)(W2 + ((size_t)(b * H_ + h0 + h)) * D_ + d0 + d4);
#pragma unroll
            for (int j = 0; j < 4; j++) tile[(d4 + j) * 64 + h] = f2bf(v[j]);
        }
        __syncthreads();
        int r = t >> 3, c = t & 7;
        int d = d0 + r;
        u32x4 v = *(const u32x4*)(tile + r * 64 + c * 8);
        *(u32x4*)((char*)w2s + (size_t)(b * 4 + ht) * 16384 + d * 128 + ((c ^ (d & 7)) << 4)) = v;
    } else if (blk < 768) {                // W1 [b][d][h] -> w1t [b][h][d] plain
        int a = blk - 512;
        int b = a >> 3, dt = (a >> 2) & 1, ht = a & 3;
        int d0 = dt * 64, h0 = ht * 64;
#pragma unroll
        for (int i = 0; i < 4; i++) {
            int idx = t + i * 256;                 // 0..1023
            int d = idx >> 4, h4 = (idx & 15) * 4;
            f32x4 v = *(const f32x4*)(W1 + ((size_t)(b * D_ + d0 + d)) * H_ + h0 + h4);
#pragma unroll
            for (int j = 0; j < 4; j++) tile[(h4 + j) * 64 + d] = f2bf(v[j]);
        }
        __syncthreads();
#pragma unroll
        for (int i = 0; i < 2; i++) {
            int idx = t + i * 256;                 // 0..511
            int h = idx >> 3, c = idx & 7;
            u32x4 v = *(const u32x4*)(tile + h * 64 + c * 8);
            *(u32x4*)(w1t + ((size_t)(b * H_ + h0 + h)) * D_ + d0 + c * 8) = v;
        }
    } else {                               // Wq
        int i = (blk - 768) * 256 + t;
        wq_bf[i] = f2bf(Wq[i]);
    }
}

// ---------------- GEMM1: q = silu(x@Wq^T); write pre-swizzled q tile images + sumsq ----
__global__ __launch_bounds__(256, 2) void k_qproj(
        const float* __restrict__ x, const unsigned short* __restrict__ wq_bf,
        unsigned short* __restrict__ q_ws, float* __restrict__ part) {
    __shared__ __align__(16) unsigned short lds_a[128 * 128];
    __shared__ __align__(16) unsigned short lds_b[128 * 128];
    __shared__ float lds_ss[4][128];

    int tid = threadIdx.x;
    int lane = tid & 63, w = tid >> 6;
    int g = lane >> 4, c15 = lane & 15;
    int blk = blockIdx.x;
    int b = blk >> 6, st = blk & 63;
    size_t rowbase = (size_t)b * S_ + (size_t)st * 128;
    const float* xg = x + rowbase * D_;

    char* pA = (char*)lds_a;
    char* pB = (char*)lds_b;

#pragma unroll
    for (int i = 0; i < 8; i++) {          // stage Wq swizzled
        int idx = tid + i * 256;
        int row = idx >> 4, cb = idx & 15;
        u32x4 v = *(const u32x4*)(wq_bf + row * 128 + cb * 8);
        *(u32x4*)(pB + row * 256 + (((unsigned)cb ^ (unsigned)(row & 7)) << 4)) = v;
    }
#pragma unroll
    for (int i = 0; i < 16; i++) {         // stage x tile bf16 swizzled
        int idx = tid + i * 256;
        int row = idx >> 5, c4 = idx & 31;
        f32x4 v = *(const f32x4*)(xg + (size_t)row * 128 + c4 * 4);
        union { unsigned short s[4]; unsigned long long u; } o;
        o.s[0] = f2bf(v[0]); o.s[1] = f2bf(v[1]); o.s[2] = f2bf(v[2]); o.s[3] = f2bf(v[3]);
        *(unsigned long long*)(pA + row * 256 + ((c4 * 8) ^ ((row & 7) << 4))) = o.u;
    }
    __syncthreads();

    f32x4 acc[2][8];
#pragma unroll
    for (int m = 0; m < 2; m++)
#pragma unroll
        for (int n = 0; n < 8; n++) acc[m][n] = (f32x4)0.0f;

#pragma unroll
    for (int kk = 0; kk < 4; kk++) {
        int kb = kk * 64 + (g << 4);
        bf16x8 a[2];
#pragma unroll
        for (int m = 0; m < 2; m++) {
            int row = (w << 5) + (m << 4) + c15;
            a[m] = *(const bf16x8*)(pA + row * 256 + (kb ^ ((row & 7) << 4)));
        }
#pragma unroll
        for (int n = 0; n < 8; n++) {
            int rowb = (n << 4) + c15;
            bf16x8 bb = *(const bf16x8*)(pB + rowb * 256 + (kb ^ ((rowb & 7) << 4)));
#pragma unroll
            for (int m = 0; m < 2; m++)
                acc[m][n] = __builtin_amdgcn_mfma_f32_16x16x32_bf16(a[m], bb, acc[m][n], 0, 0, 0);
        }
    }

    // silu (f32) + column sumsq from f32
    float ss[8];
#pragma unroll
    for (int n = 0; n < 8; n++) ss[n] = 0.0f;
#pragma unroll
    for (int m = 0; m < 2; m++)
#pragma unroll
        for (int n = 0; n < 8; n++)
#pragma unroll
            for (int r = 0; r < 4; r++) {
                float v = silu_f(acc[m][n][r]);
                acc[m][n][r] = v;
                ss[n] += v * v;
            }
#pragma unroll
    for (int n = 0; n < 8; n++) {
        float v = ss[n];
        v += __shfl_xor(v, 16, 64);
        v += __shfl_xor(v, 32, 64);
        if (lane < 16) lds_ss[w][(n << 4) + lane] = v;
    }
    __syncthreads();   // all MFMA LDS reads + lds_ss writes done

    // write q bf16 into lds_a as the swizzled tile image
#pragma unroll
    for (int m = 0; m < 2; m++)
#pragma unroll
        for (int n = 0; n < 8; n++)
#pragma unroll
            for (int r = 0; r < 4; r++) {
                int row = (w << 5) + (m << 4) + (g << 2) + r;
                int col = (n << 4) + c15;
                int byte = row * 256 + (((col >> 3) ^ (row & 7)) << 4) + ((col & 7) * 2);
                *(unsigned short*)(pA + byte) = f2bf(acc[m][n][r]);
            }
    __syncthreads();

    char* qimg = (char*)q_ws + (size_t)(b * 64 + st) * 32768;
#pragma unroll
    for (int i = 0; i < 8; i++) {
        int off = tid * 16 + i * 4096;
        *(u32x4*)(qimg + off) = *(const u32x4*)(pA + off);
    }
    if (tid < 128) {
        float s = lds_ss[0][tid] + lds_ss[1][tid] + lds_ss[2][tid] + lds_ss[3][tid];
        part[((size_t)b * 64 + st) * 128 + tid] = s;
    }
}

// ---------------- scale = 1/max(||q_col||, 1e-12) ----------------
__global__ void k_scale(const float* __restrict__ part, float* __restrict__ scale) {
    int idx = blockIdx.x * 256 + threadIdx.x;   // B*D = 4096
    int b = idx >> 7, e = idx & 127;
    const float* p = part + (size_t)b * 64 * 128 + e;
    float s = 0.0f;
    for (int t = 0; t < 64; t++) s += p[t * 128];
    scale[idx] = 1.0f / fmaxf(sqrtf(s), 1e-12f);
}

// ------- w1t: scale along d, convert in-place to pre-swizzled 16KB images -------
__global__ void k_wscale(unsigned short* __restrict__ w1t, const float* __restrict__ scale) {
    int blk = blockIdx.x;                   // 128 = b*4 + hc
    int b = blk >> 2;
    char* region = (char*)w1t + (size_t)blk * 16384;
    int t = threadIdx.x;
    u32x4 v[4]; int hh[4], cc[4];
#pragma unroll
    for (int i = 0; i < 4; i++) {
        int cid = t + i * 256;              // 0..1023
        hh[i] = cid >> 4; cc[i] = cid & 15;
        v[i] = *(const u32x4*)(region + hh[i] * 256 + cc[i] * 16);
    }
    __syncthreads();
#pragma unroll
    for (int i = 0; i < 4; i++) {
        union { unsigned short s[8]; u32x4 u; } o;
        const unsigned short* pv = (const unsigned short*)&v[i];
        const float* sc = scale + b * D_ + cc[i] * 8;
#pragma unroll
        for (int j = 0; j < 8; j++) o.s[j] = f2bf(bf2f(pv[j]) * sc[j]);
        *(u32x4*)(region + hh[i] * 256 + ((cc[i] ^ (hh[i] & 7)) << 4)) = o.u;
    }
}

// ---------------- fused per-batch MLP + LN + residual ----------------
__global__ __launch_bounds__(256, 2) void k_mlp(
        const unsigned short* __restrict__ q_img, const float* __restrict__ scale,
        const unsigned short* __restrict__ w1s, const unsigned short* __restrict__ w2s,
        const float* __restrict__ b1, const float* __restrict__ b2,
        const float* __restrict__ gamma, const float* __restrict__ beta,
        float* __restrict__ out) {
    __shared__ __align__(16) char lds[81920];
    // [0,32768): q image; [32768,49152): w1 image; [49152,65536): w2 image;
    // [65536,81920): h-scratch, 4KB per wave (wave-private, no barriers)
    int tid = threadIdx.x;
    int lane = tid & 63, w = tid >> 6;
    int g = lane >> 4, c15 = lane & 15;
    int blk = blockIdx.x;
    int b = blk >> 6, st = blk & 63;

    const char* qimg = (const char*)q_img + (size_t)(b * 64 + st) * 32768;
    const char* w1img = (const char*)w1s + (size_t)(b * 4) * 16384;
    const char* w2img = (const char*)w2s + (size_t)(b * 4) * 16384;

    // stage q (32KB) + weights for hc=0 (32KB) via global_load_lds
#pragma unroll
    for (int i = 0; i < 8; i++) {
        int off = w * 1024 + i * 4096;
        gl16(qimg + off + lane * 16, lds + off);
    }
#pragma unroll
    for (int i = 0; i < 4; i++) {
        int off = w * 1024 + i * 4096;
        gl16(w1img + off + lane * 16, lds + 32768 + off);
        gl16(w2img + off + lane * 16, lds + 49152 + off);
    }
    __syncthreads();

    f32x4 acco[2][8];
#pragma unroll
    for (int sm = 0; sm < 2; sm++)
#pragma unroll
        for (int dn = 0; dn < 8; dn++) acco[sm][dn] = (f32x4)0.0f;

#pragma unroll 1
    for (int hc = 0; hc < 4; hc++) {
        f32x4 b1v[4];
#pragma unroll
        for (int n = 0; n < 4; n++)
            b1v[n] = *(const f32x4*)(b1 + b * H_ + hc * 64 + n * 16 + g * 4);

        // GEMM2 (swapped): D = h^T tiles; A = W1 rows h, B = q cols s
        f32x4 acch[2][4];
#pragma unroll
        for (int sm = 0; sm < 2; sm++)
#pragma unroll
            for (int n = 0; n < 4; n++) acch[sm][n] = (f32x4)0.0f;
#pragma unroll
        for (int kk = 0; kk < 4; kk++) {
            bf16x8 qf[2];
#pragma unroll
            for (int sm = 0; sm < 2; sm++) {
                int row = w * 32 + sm * 16 + c15;
                qf[sm] = *(const bf16x8*)(lds + row * 256 + (((kk * 4 + g) ^ (row & 7)) << 4));
            }
#pragma unroll
            for (int n = 0; n < 4; n++) {
                int row = n * 16 + c15;
                bf16x8 wf = *(const bf16x8*)(lds + 32768 + row * 256 + (((kk * 4 + g) ^ (row & 7)) << 4));
#pragma unroll
                for (int sm = 0; sm < 2; sm++)
                    acch[sm][n] = __builtin_amdgcn_mfma_f32_16x16x32_bf16(wf, qf[sm], acch[sm][n], 0, 0, 0);
            }
        }

        // silu(+b1) -> bf16 pairs -> wave-private h scratch (b64 writes)
#pragma unroll
        for (int sm = 0; sm < 2; sm++) {
            int rl = sm * 16 + c15;
#pragma unroll
            for (int n = 0; n < 4; n++) {
                float v0 = silu_f(acch[sm][n][0] + b1v[n][0]);
                float v1 = silu_f(acch[sm][n][1] + b1v[n][1]);
                float v2 = silu_f(acch[sm][n][2] + b1v[n][2]);
                float v3 = silu_f(acch[sm][n][3] + b1v[n][3]);
                unsigned int lo = cvtpk(v0, v1), hi = cvtpk(v2, v3);
                int byte = 65536 + w * 4096 + rl * 128 + ((n * 32 + g * 8) ^ ((rl & 7) << 4));
                *(unsigned long long*)(lds + byte) =
                    ((unsigned long long)hi << 32) | (unsigned long long)lo;
            }
        }

        // GEMM3: acco += h @ W2c
#pragma unroll
        for (int kt = 0; kt < 2; kt++) {
            bf16x8 ha[2];
#pragma unroll
            for (int sm = 0; sm < 2; sm++) {
                int rl = sm * 16 + c15;
                ha[sm] = *(const bf16x8*)(lds + 65536 + w * 4096 + rl * 128 +
                                          ((kt * 64 + g * 16) ^ ((rl & 7) << 4)));
            }
#pragma unroll
            for (int dn = 0; dn < 8; dn++) {
                int row = dn * 16 + c15;
                bf16x8 wf = *(const bf16x8*)(lds + 49152 + row * 128 + (((kt * 4 + g) ^ (row & 7)) << 4));
#pragma unroll
                for (int sm = 0; sm < 2; sm++)
                    acco[sm][dn] = __builtin_amdgcn_mfma_f32_16x16x32_bf16(ha[sm], wf, acco[sm][dn], 0, 0, 0);
            }
        }

        if (hc < 3) {
            __syncthreads();
#pragma unroll
            for (int i = 0; i < 4; i++) {
                int off = w * 1024 + i * 4096;
                gl16(w1img + (hc + 1) * 16384 + off + lane * 16, lds + 32768 + off);
                gl16(w2img + (hc + 1) * 16384 + off + lane * 16, lds + 49152 + off);
            }
            __syncthreads();
        }
    }

    // epilogue: LayerNorm over D + residual q*scale
    float scv[8], gv[8], bev[8], b2v[8];
#pragma unroll
    for (int dn = 0; dn < 8; dn++) {
        int col = dn * 16 + c15;
        scv[dn] = scale[b * 128 + col];
        gv[dn] = gamma[b * 128 + col];
        bev[dn] = beta[b * 128 + col];
        b2v[dn] = b2[b * 128 + col];
    }
    float* og = out + ((size_t)b * S_ + (size_t)st * 128) * D_;
#pragma unroll
    for (int sm = 0; sm < 2; sm++) {
#pragma unroll
        for (int r = 0; r < 4; r++) {
            int row = w * 32 + sm * 16 + g * 4 + r;
            float v[8];
            float s = 0.0f, s2 = 0.0f;
#pragma unroll
            for (int dn = 0; dn < 8; dn++) {
                v[dn] = acco[sm][dn][r] + b2v[dn];
                s += v[dn]; s2 += v[dn] * v[dn];
            }
            s += __shfl_xor(s, 1, 64);  s2 += __shfl_xor(s2, 1, 64);
            s += __shfl_xor(s, 2, 64);  s2 += __shfl_xor(s2, 2, 64);
            s += __shfl_xor(s, 4, 64);  s2 += __shfl_xor(s2, 4, 64);
            s += __shfl_xor(s, 8, 64);  s2 += __shfl_xor(s2, 8, 64);
            float mu = s * (1.0f / 128.0f);
            float var = s2 * (1.0f / 128.0f) - mu * mu;
            float rstd = rsqrtf(var + 1e-5f);
#pragma unroll
            for (int dn = 0; dn < 8; dn++) {
                int col = dn * 16 + c15;
                int byte = row * 256 + (((col >> 3) ^ (row & 7)) << 4) + ((col & 7) * 2);
                float qv = bf2f(*(const unsigned short*)(lds + byte)) * scv[dn];
                og[(size_t)row * 128 + col] = (v[dn] - mu) * rstd * gv[dn] + bev[dn] + qv;
            }
        }
    }
}

extern "C" void kernel_launch(void* const* d_in, const int* in_sizes, int n_in,
                              void* d_out, int out_size, void* d_ws, size_t ws_size,
                              hipStream_t stream) {
    (void)in_sizes; (void)n_in; (void)out_size; (void)ws_size;
    const float* x     = (const float*)d_in[0];
    const float* Wq    = (const float*)d_in[1];
    const float* W1    = (const float*)d_in[2];
    const float* b1    = (const float*)d_in[3];
    const float* W2    = (const float*)d_in[4];
    const float* b2    = (const float*)d_in[5];
    const float* gamma = (const float*)d_in[6];
    const float* beta  = (const float*)d_in[7];
    float* out = (float*)d_out;

    char* ws = (char*)d_ws;
    unsigned short* wq_bf = (unsigned short*)(ws);                       // 32KB
    unsigned short* w1t   = (unsigned short*)(ws + 32768);               // 2MB (becomes w1s images)
    unsigned short* w2s   = (unsigned short*)(ws + 32768 + 2097152);     // 2MB images
    float* part           = (float*)(ws + 32768 + 2 * 2097152);          // 1MB
    float* scale          = (float*)(ws + 32768 + 2 * 2097152 + 1048576);// 16KB
    unsigned short* q_ws  = (unsigned short*)(ws + 32768 + 2 * 2097152 + 1048576 + 16384); // 64MB

    hipLaunchKernelGGL(k_prep, dim3(832), dim3(256), 0, stream, Wq, W1, W2, wq_bf, w1t, w2s);
    hipLaunchKernelGGL(k_qproj, dim3(2048), dim3(256), 0, stream, x, wq_bf, q_ws, part);
    hipLaunchKernelGGL(k_scale, dim3(16), dim3(256), 0, stream, part, scale);
    hipLaunchKernelGGL(k_wscale, dim3(128), dim3(256), 0, stream, w1t, scale);
    hipLaunchKernelGGL(k_mlp, dim3(2048), dim3(256), 0, stream,
                       q_ws, scale, w1t, w2s, b1, b2, gamma, beta, out);
}